// Round 6
// baseline (267.324 us; speedup 1.0000x reference)
//
#include <hip/hip_runtime.h>
#include <cstdint>
#include <cstddef>

#define NTH 256
#define NGT 128
#define BATCH 16
#define NC 80
#define G 16                   // GTs per block
#define NCHUNK (NGT / G)       // 8
#define HW0 25600
#define HW1 6400
#define HW2 1600
#define NBLK (3 * BATCH * NCHUNK)   // 384 fused scan+loss blocks

__device__ __forceinline__ unsigned long long umin64(unsigned long long a, unsigned long long b) {
    return a < b ? a : b;
}

#define EVAL(px, py, idx_) do {                                                   \
    _Pragma("unroll")                                                             \
    for (int g = 0; g < G; ++g) {                                                 \
        float dx = gx[g] - (px), dy = gy[g] - (py);                               \
        float d2 = dx * dx + dy * dy;                                             \
        unsigned long long key =                                                  \
            ((unsigned long long)__float_as_uint(d2) << 32) | (unsigned)(idx_);   \
        kmin[g] = umin64(kmin[g], key);                                           \
    } } while (0)

// Fused scan+loss: one block per (level, batch, chunk-of-16-GTs); NO hw
// slicing, so each block's argmin is already global for its GTs and the loss
// is computed inline. No atomics, no fences (R3/R5 lesson: same-address
// device RMWs serialize at ~31 cyc — 1536 of them cost ~20 us).
// u64 key (d2 bits << 32 | idx): min == min-d2 with first-index tie-break,
// exactly matching jnp.argmin (d2 >= 0 so float bits are monotone unsigned).
// Each block writes ONE partial (ce,l1,w) triple to its own slot.
__global__ __launch_bounds__(NTH) void scan_loss_kernel(
    const float* __restrict__ cls0, const float* __restrict__ cls1, const float* __restrict__ cls2,
    const float* __restrict__ reg0, const float* __restrict__ reg1, const float* __restrict__ reg2,
    const float* __restrict__ gt_boxes, const int* __restrict__ gt_labels,
    float* __restrict__ partl)
{
    const int x = blockIdx.x;
    const int lvl = x >> 7;            // 128 blocks per level
    const int y = x & 127;
    const int b = y >> 3, chunk = y & 7;

    const float* cls; const float* reg; int HW;
    if (lvl == 0)      { cls = cls0; reg = reg0; HW = HW0; }
    else if (lvl == 1) { cls = cls1; reg = reg1; HW = HW1; }
    else               { cls = cls2; reg = reg2; HW = HW2; }

    const int tid = threadIdx.x, wave = tid >> 6, lane = tid & 63;
    const int n0 = chunk * G;

    // GT xy (block-uniform addresses -> scalar loads)
    float gx[G], gy[G];
#pragma unroll
    for (int g = 0; g < G; ++g) {
        const float* gb = gt_boxes + (size_t)(b * NGT + n0 + g) * 4;
        gx[g] = gb[0]; gy[g] = gb[1];
    }

    unsigned long long kmin[G];
#pragma unroll
    for (int g = 0; g < G; ++g) kmin[g] = ~0ull;

    // coalesced float4 row loads (16 B/lane, full line utilization; zw unused)
    const float4* base = reinterpret_cast<const float4*>(reg) + (size_t)b * HW;
    for (int i = tid; i < HW; i += NTH) {
        float4 p = base[i];
        EVAL(p.x, p.y, i);
    }

    // intra-wave butterfly reduction per GT
#pragma unroll
    for (int g = 0; g < G; ++g) {
#pragma unroll
        for (int off = 32; off >= 1; off >>= 1) {
            unsigned long long o = __shfl_down(kmin[g], off, 64);
            kmin[g] = umin64(kmin[g], o);
        }
    }

    __shared__ unsigned long long smem[G][4];
    if (lane == 0) {
#pragma unroll
        for (int g = 0; g < G; ++g) smem[g][wave] = kmin[g];
    }
    __syncthreads();

    __shared__ unsigned long long keyf[G];
    if (tid < G) {
        keyf[tid] = umin64(umin64(smem[tid][0], smem[tid][1]),
                           umin64(smem[tid][2], smem[tid][3]));
    }
    __syncthreads();

    // Loss phase: wave w handles GTs 4w..4w+3 sequentially.
    float ce_acc = 0.0f, l1_acc = 0.0f, w_acc = 0.0f;
#pragma unroll
    for (int j = 0; j < 4; ++j) {
        const int g = wave * 4 + j;
        unsigned long long key = keyf[g];
        int match = (int)(unsigned)(key & 0xffffffffu);
        float d2min = __uint_as_float((unsigned)(key >> 32));
        bool valid = d2min < 6.25f;      // sqrt(d2) < 2.5; wave-uniform
        if (!valid) continue;

        const int n = n0 + g;
        const int label = gt_labels[b * NGT + n];
        const float* c = cls + ((size_t)b * HW + match) * NC;

        // 80-class log-softmax: lanes 0..63 hold c[lane], lanes 0..15 also c[64+lane]
        float x1 = c[lane];
        float x2 = (lane < NC - 64) ? c[64 + lane] : -INFINITY;
        float mx = fmaxf(x1, x2);
#pragma unroll
        for (int off = 32; off >= 1; off >>= 1) mx = fmaxf(mx, __shfl_xor(mx, off, 64));
        float s = expf(x1 - mx) + ((lane < NC - 64) ? expf(x2 - mx) : 0.0f);
#pragma unroll
        for (int off = 32; off >= 1; off >>= 1) s += __shfl_xor(s, off, 64);

        if (lane == 0) {
            ce_acc += -(c[label] - mx - logf(s));
            const float* gb = gt_boxes + (size_t)(b * NGT + n) * 4;
            const float* gr = reg + ((size_t)b * HW + match) * 4;
            l1_acc += fabsf(gr[0] - gb[0]) + fabsf(gr[1] - gb[1]) +
                      fabsf(gr[2] - gb[2]) + fabsf(gr[3] - gb[3]);
            w_acc += 1.0f;
        }
    }

    __shared__ float cw[4][3];
    if (lane == 0) { cw[wave][0] = ce_acc; cw[wave][1] = l1_acc; cw[wave][2] = w_acc; }
    __syncthreads();

    if (tid == 0) {
        float* o = partl + (size_t)blockIdx.x * 3;
        o[0] = cw[0][0] + cw[1][0] + cw[2][0] + cw[3][0];
        o[1] = cw[0][1] + cw[1][1] + cw[2][1] + cw[3][1];
        o[2] = cw[0][2] + cw[1][2] + cw[2][2] + cw[3][2];
    }
}

// Deterministic tree reduction of the 384 partial triples; writes outputs.
__global__ __launch_bounds__(NTH) void finalize_kernel(
    const float* __restrict__ partl, float* __restrict__ out)
{
    const int tid = threadIdx.x, wave = tid >> 6, lane = tid & 63;
    float ce = 0.0f, l1 = 0.0f, w = 0.0f;
    for (int i = tid; i < NBLK; i += NTH) {
        ce += partl[(size_t)i * 3 + 0];
        l1 += partl[(size_t)i * 3 + 1];
        w  += partl[(size_t)i * 3 + 2];
    }
#pragma unroll
    for (int off = 32; off >= 1; off >>= 1) {
        ce += __shfl_xor(ce, off, 64);
        l1 += __shfl_xor(l1, off, 64);
        w  += __shfl_xor(w,  off, 64);
    }
    __shared__ float sm[3][4];
    if (lane == 0) { sm[0][wave] = ce; sm[1][wave] = l1; sm[2][wave] = w; }
    __syncthreads();
    if (tid == 0) {
        float tce = sm[0][0] + sm[0][1] + sm[0][2] + sm[0][3];
        float tl1 = sm[1][0] + sm[1][1] + sm[1][2] + sm[1][3];
        float tw  = sm[2][0] + sm[2][1] + sm[2][2] + sm[2][3];
        float denom = fmaxf(tw, 1.0f);
        out[0] = tce / denom;
        out[1] = tl1 / denom;
        out[2] = tw;
    }
}

extern "C" void kernel_launch(void* const* d_in, const int* in_sizes, int n_in,
                              void* d_out, int out_size, void* d_ws, size_t ws_size,
                              hipStream_t stream) {
    // Map inputs BY SIZE (dict order interleaves cls/reg; all sizes distinct).
    const float* cls0 = nullptr; const float* cls1 = nullptr; const float* cls2 = nullptr;
    const float* reg0 = nullptr; const float* reg1 = nullptr; const float* reg2 = nullptr;
    const float* gt_boxes = nullptr; const int* gt_labels = nullptr;
    for (int i = 0; i < n_in; ++i) {
        switch (in_sizes[i]) {
            case BATCH * HW0 * NC: cls0 = (const float*)d_in[i]; break;
            case BATCH * HW1 * NC: cls1 = (const float*)d_in[i]; break;
            case BATCH * HW2 * NC: cls2 = (const float*)d_in[i]; break;
            case BATCH * HW0 * 4:  reg0 = (const float*)d_in[i]; break;
            case BATCH * HW1 * 4:  reg1 = (const float*)d_in[i]; break;
            case BATCH * HW2 * 4:  reg2 = (const float*)d_in[i]; break;
            case BATCH * NGT * 4:  gt_boxes = (const float*)d_in[i]; break;
            case BATCH * NGT:      gt_labels = (const int*)d_in[i]; break;
            default: break;
        }
    }

    float* partl = (float*)d_ws;   // 384*3 floats; fully overwritten every launch

    scan_loss_kernel<<<NBLK, NTH, 0, stream>>>(
        cls0, cls1, cls2, reg0, reg1, reg2, gt_boxes, gt_labels, partl);

    finalize_kernel<<<1, NTH, 0, stream>>>(partl, (float*)d_out);
}

// Round 7
// 221.092 us; speedup vs baseline: 1.2091x; 1.2091x over previous
//
#include <hip/hip_runtime.h>
#include <cstdint>
#include <cstddef>

#define NTH 256
#define NGT 128
#define BATCH 16
#define NC 80
#define G 16                  // GTs per scan block
#define NCHUNK (NGT / G)      // 8
#define HW0 25600
#define HW1 6400
#define HW2 1600
#define SL0 8                 // hw slices per level (seg: 3200/3200/1600)
#define SL1 2
#define SL2 1
#define MAXSL 8
#define NB0 (BATCH * NCHUNK * SL0)   // 1024
#define NB1 (BATCH * NCHUNK * SL1)   //  256
#define NB2 (BATCH * NCHUNK * SL2)   //  128
#define SCAN_GRID (NB0 + NB1 + NB2)  // 1408 blocks = 5632 waves, all co-resident
#define NLOSS_BLK (3 * BATCH * NGT / 4)   // 1536 loss blocks (4 GTs each)

// ws layout (bytes)
#define PART_OFF   0
#define PART_BYTES (3 * BATCH * NGT * MAXSL * 8)          // 393,216
#define PARTL_OFF  PART_BYTES
#define PARTL_BYTES (NLOSS_BLK * 3 * (int)sizeof(float))  // 18,432

__device__ __forceinline__ unsigned long long umin64(unsigned long long a, unsigned long long b) {
    return a < b ? a : b;
}

#define EVAL(px, py, idx_) do {                                                   \
    _Pragma("unroll")                                                             \
    for (int g = 0; g < G; ++g) {                                                 \
        float dx = gx[g] - (px), dy = gy[g] - (py);                               \
        float d2 = dx * dx + dy * dy;                                             \
        unsigned long long key =                                                  \
            ((unsigned long long)__float_as_uint(d2) << 32) | (unsigned)(idx_);   \
        kmin[g] = umin64(kmin[g], key);                                           \
    } } while (0)

// Scan: one block per (level, batch, hw-slice, chunk-of-16-GTs), sliced so
// every block does ~12.5 iterations and ALL 5632 waves are co-resident
// (R6 lesson: unsliced lvl-0 left 1 wave/SIMD exposed to full load latency).
// Coalesced float4 row loads; u64 key (d2 bits << 32 | idx): min == min-d2
// with first-index tie-break, exactly matching jnp.argmin. No atomics.
__global__ __launch_bounds__(NTH) void scan_kernel(
    const float4* __restrict__ reg0, const float4* __restrict__ reg1, const float4* __restrict__ reg2,
    const float* __restrict__ gt_boxes,
    unsigned long long* __restrict__ part)
{
    int x = blockIdx.x;
    int lvl, b, slice, chunk, HW, nsl;
    const float4* src;
    if (x < NB0) {
        lvl = 0; b = x / (NCHUNK * SL0);
        int r = x % (NCHUNK * SL0);
        chunk = r % NCHUNK; slice = r / NCHUNK;
        HW = HW0; nsl = SL0; src = reg0;
    } else if (x < NB0 + NB1) {
        int y = x - NB0;
        lvl = 1; b = y / (NCHUNK * SL1);
        int r = y % (NCHUNK * SL1);
        chunk = r % NCHUNK; slice = r / NCHUNK;
        HW = HW1; nsl = SL1; src = reg1;
    } else {
        int y = x - NB0 - NB1;
        lvl = 2; b = y / NCHUNK; chunk = y % NCHUNK; slice = 0;
        HW = HW2; nsl = SL2; src = reg2;
    }

    const int seg = HW / nsl;
    const int e0 = slice * seg, e1 = e0 + seg;
    const int tid = threadIdx.x, wave = tid >> 6, lane = tid & 63;
    const int n0 = chunk * G;

    // GT xy (block-uniform addresses -> scalar loads)
    float gx[G], gy[G];
#pragma unroll
    for (int g = 0; g < G; ++g) {
        const float* gb = gt_boxes + (size_t)(b * NGT + n0 + g) * 4;
        gx[g] = gb[0]; gy[g] = gb[1];
    }

    unsigned long long kmin[G];
#pragma unroll
    for (int g = 0; g < G; ++g) kmin[g] = ~0ull;

    const float4* base = src + (size_t)b * HW;
    for (int i = e0 + tid; i < e1; i += NTH) {
        float4 p = base[i];
        EVAL(p.x, p.y, i);
    }

    // intra-wave butterfly reduction per GT
#pragma unroll
    for (int g = 0; g < G; ++g) {
#pragma unroll
        for (int off = 32; off >= 1; off >>= 1) {
            unsigned long long o = __shfl_down(kmin[g], off, 64);
            kmin[g] = umin64(kmin[g], o);
        }
    }

    __shared__ unsigned long long smem[G][4];
    if (lane == 0) {
#pragma unroll
        for (int g = 0; g < G; ++g) smem[g][wave] = kmin[g];
    }
    __syncthreads();

    if (tid < G) {
        unsigned long long key = umin64(umin64(smem[tid][0], smem[tid][1]),
                                        umin64(smem[tid][2], smem[tid][3]));
        part[((size_t)(lvl * BATCH + b) * NGT + n0 + tid) * MAXSL + slice] = key;
    }
}

// Loss: one wave per (level, batch, gt); 4 waves per block. No same-address
// atomics (R3/R5 lesson: serialized device RMWs cost ~31 cyc each). Each
// block combines slice partials and writes ONE partial triple to its slot.
__global__ __launch_bounds__(NTH) void loss_kernel(
    const float* __restrict__ cls0, const float* __restrict__ cls1, const float* __restrict__ cls2,
    const float* __restrict__ reg0, const float* __restrict__ reg1, const float* __restrict__ reg2,
    const float* __restrict__ gt_boxes, const int* __restrict__ gt_labels,
    const unsigned long long* __restrict__ part, float* __restrict__ partl)
{
    const int wave = threadIdx.x >> 6;
    const int lane = threadIdx.x & 63;
    const int gid = blockIdx.x * 4 + wave;     // 0..6143
    const int lvl = gid / (BATCH * NGT);
    const int r = gid % (BATCH * NGT);
    const int b = r / NGT, n = r % NGT;

    const float* cls; const float* reg; int HW, S;
    if (lvl == 0)      { cls = cls0; reg = reg0; HW = HW0; S = SL0; }
    else if (lvl == 1) { cls = cls1; reg = reg1; HW = HW1; S = SL1; }
    else               { cls = cls2; reg = reg2; HW = HW2; S = SL2; }

    const unsigned long long* p = part + (size_t)gid * MAXSL;
    unsigned long long key = p[0];
    for (int s = 1; s < S; ++s) key = umin64(key, p[s]);

    int match = (int)(unsigned)(key & 0xffffffffu);
    float d2min = __uint_as_float((unsigned)(key >> 32));
    bool valid = d2min < 6.25f;  // sqrt(d2) < 2.5

    const int label = gt_labels[b * NGT + n];
    const float* c = cls + ((size_t)b * HW + match) * NC;

    // 80-class log-softmax: lanes 0..63 hold c[lane], lanes 0..15 also c[64+lane]
    float x1 = c[lane];
    float x2 = (lane < NC - 64) ? c[64 + lane] : -INFINITY;
    float mx = fmaxf(x1, x2);
#pragma unroll
    for (int off = 32; off >= 1; off >>= 1) mx = fmaxf(mx, __shfl_xor(mx, off, 64));
    float s = expf(x1 - mx) + ((lane < NC - 64) ? expf(x2 - mx) : 0.0f);
#pragma unroll
    for (int off = 32; off >= 1; off >>= 1) s += __shfl_xor(s, off, 64);

    __shared__ float ce_s[4], l1_s[4], w_s[4];
    if (lane == 0) {
        float ce = 0.0f, l1 = 0.0f, w = 0.0f;
        if (valid) {
            float xlab = c[label];
            ce = -(xlab - mx - logf(s));
            const float* gb = gt_boxes + (size_t)(b * NGT + n) * 4;
            const float* gr = reg + ((size_t)b * HW + match) * 4;
            l1 = fabsf(gr[0] - gb[0]) + fabsf(gr[1] - gb[1]) +
                 fabsf(gr[2] - gb[2]) + fabsf(gr[3] - gb[3]);
            w = 1.0f;
        }
        ce_s[wave] = ce; l1_s[wave] = l1; w_s[wave] = w;
    }
    __syncthreads();

    if (threadIdx.x == 0) {
        float* o = partl + (size_t)blockIdx.x * 3;
        o[0] = ce_s[0] + ce_s[1] + ce_s[2] + ce_s[3];
        o[1] = l1_s[0] + l1_s[1] + l1_s[2] + l1_s[3];
        o[2] = w_s[0] + w_s[1] + w_s[2] + w_s[3];
    }
}

// Deterministic tree reduction of the 1536 partial triples; writes outputs.
__global__ __launch_bounds__(NTH) void finalize_kernel(
    const float* __restrict__ partl, float* __restrict__ out)
{
    const int tid = threadIdx.x, wave = tid >> 6, lane = tid & 63;
    float ce = 0.0f, l1 = 0.0f, w = 0.0f;
    for (int i = tid; i < NLOSS_BLK; i += NTH) {
        ce += partl[(size_t)i * 3 + 0];
        l1 += partl[(size_t)i * 3 + 1];
        w  += partl[(size_t)i * 3 + 2];
    }
#pragma unroll
    for (int off = 32; off >= 1; off >>= 1) {
        ce += __shfl_xor(ce, off, 64);
        l1 += __shfl_xor(l1, off, 64);
        w  += __shfl_xor(w,  off, 64);
    }
    __shared__ float sm[3][4];
    if (lane == 0) { sm[0][wave] = ce; sm[1][wave] = l1; sm[2][wave] = w; }
    __syncthreads();
    if (tid == 0) {
        float tce = sm[0][0] + sm[0][1] + sm[0][2] + sm[0][3];
        float tl1 = sm[1][0] + sm[1][1] + sm[1][2] + sm[1][3];
        float tw  = sm[2][0] + sm[2][1] + sm[2][2] + sm[2][3];
        float denom = fmaxf(tw, 1.0f);
        out[0] = tce / denom;
        out[1] = tl1 / denom;
        out[2] = tw;
    }
}

extern "C" void kernel_launch(void* const* d_in, const int* in_sizes, int n_in,
                              void* d_out, int out_size, void* d_ws, size_t ws_size,
                              hipStream_t stream) {
    // Map inputs BY SIZE (dict order interleaves cls/reg; all sizes distinct).
    const float* cls0 = nullptr; const float* cls1 = nullptr; const float* cls2 = nullptr;
    const float* reg0 = nullptr; const float* reg1 = nullptr; const float* reg2 = nullptr;
    const float* gt_boxes = nullptr; const int* gt_labels = nullptr;
    for (int i = 0; i < n_in; ++i) {
        switch (in_sizes[i]) {
            case BATCH * HW0 * NC: cls0 = (const float*)d_in[i]; break;
            case BATCH * HW1 * NC: cls1 = (const float*)d_in[i]; break;
            case BATCH * HW2 * NC: cls2 = (const float*)d_in[i]; break;
            case BATCH * HW0 * 4:  reg0 = (const float*)d_in[i]; break;
            case BATCH * HW1 * 4:  reg1 = (const float*)d_in[i]; break;
            case BATCH * HW2 * 4:  reg2 = (const float*)d_in[i]; break;
            case BATCH * NGT * 4:  gt_boxes = (const float*)d_in[i]; break;
            case BATCH * NGT:      gt_labels = (const int*)d_in[i]; break;
            default: break;
        }
    }

    char* ws = (char*)d_ws;
    unsigned long long* part = (unsigned long long*)(ws + PART_OFF);
    float* partl = (float*)(ws + PARTL_OFF);

    scan_kernel<<<SCAN_GRID, NTH, 0, stream>>>(
        (const float4*)reg0, (const float4*)reg1, (const float4*)reg2,
        gt_boxes, part);

    loss_kernel<<<NLOSS_BLK, NTH, 0, stream>>>(
        cls0, cls1, cls2, reg0, reg1, reg2, gt_boxes, gt_labels, part, partl);

    finalize_kernel<<<1, NTH, 0, stream>>>(partl, (float*)d_out);
}